// Round 11
// baseline (158.872 us; speedup 1.0000x reference)
//
#include <hip/hip_runtime.h>
#include <hip/hip_bf16.h>

// Problem constants
#define BHALF 4096      // B = 8192/2
#define DDIM 128        // feature dim per matrix
#define KCAT 384        // 3*DDIM, packed row width
#define TEMP_INV 10.0f  // 1/TEMP
#define EXP2K 14.426950408889634f  // 10 * log2(e): exp(v*10) = exp2(v*EXP2K)

typedef __attribute__((ext_vector_type(8))) short short8;   // 8 bf16
typedef __attribute__((ext_vector_type(4))) float f32x4;    // 16x16 MFMA acc

// ---------------------------------------------------------------------------
// Fused normalize + diag: one wave per (matrix, row-pair i).
__global__ __launch_bounds__(256) void norm_diag_kernel(
    const float* __restrict__ x, const float* __restrict__ y,
    const float* __restrict__ z, ushort* __restrict__ nrm1,
    ushort* __restrict__ nrm2, float* __restrict__ dxyz) {
  int wave = threadIdx.x >> 6;
  int lane = threadIdx.x & 63;
  int gi = blockIdx.x * 4 + wave;  // 0 .. 3*4096-1
  int mat = gi >> 12;
  int i = gi & 4095;
  const float* src = (mat == 0 ? x : (mat == 1 ? y : z));
  float2 a = *(const float2*)(src + (size_t)i * DDIM + lane * 2);
  float2 b = *(const float2*)(src + (size_t)(i + BHALF) * DDIM + lane * 2);
  float s1 = a.x * a.x + a.y * a.y;
  float s2 = b.x * b.x + b.y * b.y;
  float d = a.x * b.x + a.y * b.y;
#pragma unroll
  for (int m = 1; m < 64; m <<= 1) {
    s1 += __shfl_xor(s1, m, 64);
    s2 += __shfl_xor(s2, m, 64);
    d += __shfl_xor(d, m, 64);
  }
  float r1 = 1.0f / fmaxf(sqrtf(s1), 1e-12f);
  float r2 = 1.0f / fmaxf(sqrtf(s2), 1e-12f);
  ushort* d1 = nrm1 + (size_t)i * KCAT + mat * DDIM + lane * 2;
  ushort* d2 = nrm2 + (size_t)i * KCAT + mat * DDIM + lane * 2;
  __hip_bfloat162 o1, o2;
  o1.x = __float2bfloat16(a.x * r1);
  o1.y = __float2bfloat16(a.y * r1);
  o2.x = __float2bfloat16(b.x * r2);
  o2.y = __float2bfloat16(b.y * r2);
  *(__hip_bfloat162*)d1 = o1;
  *(__hip_bfloat162*)d2 = o2;
  if (lane == 0) dxyz[mat * BHALF + i] = d * r1 * r2;
}

// ---------------------------------------------------------------------------
// Flush helpers (R1/R2/R10-verified, global atomics, once per block).
// 16x16 C/D layout: col = lane&15, row = (lane>>4)*4 + r.

// g3^T (operand-swapped mfma(b,a)): D[j][i]; reduce over j = regs + xor16 +
// xor32; one value per i (nrm1 row).
__device__ __forceinline__ void flush_cheap(f32x4 (&acc)[4][4],
                                            float* __restrict__ dst, int base,
                                            int lane) {
#pragma unroll
  for (int m = 0; m < 4; ++m) {
    float s = 0.0f;
#pragma unroll
    for (int n = 0; n < 4; ++n)
#pragma unroll
      for (int r = 0; r < 4; ++r) s += exp2f(acc[m][n][r] * EXP2K);
    s += __shfl_xor(s, 16, 64);
    s += __shfl_xor(s, 32, 64);
    if (lane < 16) atomicAdd(&dst[base + m * 16 + lane], s);
  }
}

// Full flush: D[i][j]; rs[i] += sum_j exp, cs[j] += sum_i exp.
__device__ __forceinline__ void flush_full(f32x4 (&acc)[4][4],
                                           float* __restrict__ rs,
                                           float* __restrict__ cs, int rbase,
                                           int cbase, int lane) {
#pragma unroll
  for (int m = 0; m < 4; ++m)
#pragma unroll
    for (int n = 0; n < 4; ++n)
#pragma unroll
      for (int r = 0; r < 4; ++r)
        acc[m][n][r] = exp2f(acc[m][n][r] * EXP2K);

  // row sums: reduce over cols (n + xor over lane&15)
#pragma unroll
  for (int m = 0; m < 4; ++m) {
    float rsum[4];
#pragma unroll
    for (int r = 0; r < 4; ++r)
      rsum[r] = acc[m][0][r] + acc[m][1][r] + acc[m][2][r] + acc[m][3][r];
#pragma unroll
    for (int r = 0; r < 4; ++r) {
      rsum[r] += __shfl_xor(rsum[r], 1, 64);
      rsum[r] += __shfl_xor(rsum[r], 2, 64);
      rsum[r] += __shfl_xor(rsum[r], 4, 64);
      rsum[r] += __shfl_xor(rsum[r], 8, 64);
    }
    if ((lane & 15) == 0) {
      int rb = rbase + m * 16 + (lane >> 4) * 4;
#pragma unroll
      for (int r = 0; r < 4; ++r) atomicAdd(&rs[rb + r], rsum[r]);
    }
  }

  // col sums: reduce over rows (m, r, xor16, xor32)
#pragma unroll
  for (int n = 0; n < 4; ++n) {
    float csum = 0.0f;
#pragma unroll
    for (int m = 0; m < 4; ++m)
#pragma unroll
      for (int r = 0; r < 4; ++r) csum += acc[m][n][r];
    csum += __shfl_xor(csum, 16, 64);
    csum += __shfl_xor(csum, 32, 64);
    if (lane < 16) atomicAdd(&cs[cbase + n * 16 + lane], csum);
  }
}

// ---------------------------------------------------------------------------
// Gram kernel v7 "direct": NO LDS AT ALL. Inputs (9.4 MB) are L2/L3-resident;
// per Common-mistake #7, staging L2-fit data is pure overhead. Each wave
// reads its MFMA fragments straight from global:
//   af[m] = 16B at row (rowbase + wr*64 + m*16 + (lane&15)), col chunk
//           (lane>>4)*8 + t*32  — lanes {r,r+16,r+32,r+48} cover 64
//           contiguous bytes of row r -> 16 aligned 64B lines per load.
// 8 base addresses per wave; every K-step / gram column offset fits the
// 13-bit global_load immediate -> the K-loop is pure loads + MFMAs: zero
// barriers, zero waitcnt asm, zero LDS, near-zero VALU. 16K independent
// waves; LDS=0 removes any occupancy cap.
//   z-remapped gram g: z=0 -> g3 (K=384, operand-swapped) first for tail
//   balance; g0 = x1·y1^T, g1 = x1·z1^T, g2 = y1·z1^T (K=128).
// sums layout (4096 floats each): [rs0, cs0, rs1, cs1, rs2, cs2, rs3]
__global__ __launch_bounds__(256) void gram_direct_kernel(
    const ushort* __restrict__ nrm1, const ushort* __restrict__ nrm2,
    float* __restrict__ sums) {
  int tid = threadIdx.x;
  int lane = tid & 63;
  int wave = tid >> 6;  // 0..3
  int wr = wave >> 1;   // 0..1: rows wr*64
  int wc = wave & 1;    // 0..1: cols wc*64
  int g = (blockIdx.z == 0) ? 3 : (int)blockIdx.z - 1;  // heavy g3 first
  int rowbase = blockIdx.x * 128;
  int colbase = blockIdx.y * 128;

  const ushort* Ab;  // A rows base (incl. gram column offset)
  const ushort* Bb;  // B rows base
  int nsteps;
  float* rs;
  float* cs;
  if (g == 3) {
    Ab = nrm1;       Bb = nrm2;       nsteps = 12;
    rs = sums + 6 * 4096; cs = nullptr;
  } else if (g == 0) {
    Ab = nrm1;       Bb = nrm1 + 128; nsteps = 4;
    rs = sums;            cs = sums + 4096;
  } else if (g == 1) {
    Ab = nrm1;       Bb = nrm1 + 256; nsteps = 4;
    rs = sums + 2 * 4096; cs = sums + 3 * 4096;
  } else {
    Ab = nrm1 + 128; Bb = nrm1 + 256; nsteps = 4;
    rs = sums + 4 * 4096; cs = sums + 5 * 4096;
  }

  // Per-lane fragment base pointers (computed once; K advances via the
  // 13-bit immediate offset t*64B, folded by the compiler).
  int rsel = lane & 15;
  int fc8 = (lane >> 4) * 8;  // ushort offset of this lane's 16B chunk
  const ushort* aP[4];
  const ushort* bP[4];
#pragma unroll
  for (int m = 0; m < 4; ++m)
    aP[m] = Ab + (size_t)(rowbase + wr * 64 + m * 16 + rsel) * KCAT + fc8;
#pragma unroll
  for (int n = 0; n < 4; ++n)
    bP[n] = Bb + (size_t)(colbase + wc * 64 + n * 16 + rsel) * KCAT + fc8;

  f32x4 acc[4][4] = {};

  if (g == 3) {
#pragma unroll 2
    for (int t = 0; t < 12; ++t) {
      short8 af[4], bf[4];
#pragma unroll
      for (int m = 0; m < 4; ++m) af[m] = *(const short8*)(aP[m] + t * 32);
#pragma unroll
      for (int n = 0; n < 4; ++n) bf[n] = *(const short8*)(bP[n] + t * 32);
#pragma unroll
      for (int m = 0; m < 4; ++m)
#pragma unroll
        for (int n = 0; n < 4; ++n)
          acc[m][n] = __builtin_amdgcn_mfma_f32_16x16x32_bf16(
              bf[n], af[m], acc[m][n], 0, 0, 0);
    }
  } else {
#pragma unroll
    for (int t = 0; t < 4; ++t) {
      short8 af[4], bf[4];
#pragma unroll
      for (int m = 0; m < 4; ++m) af[m] = *(const short8*)(aP[m] + t * 32);
#pragma unroll
      for (int n = 0; n < 4; ++n) bf[n] = *(const short8*)(bP[n] + t * 32);
#pragma unroll
      for (int m = 0; m < 4; ++m)
#pragma unroll
        for (int n = 0; n < 4; ++n)
          acc[m][n] = __builtin_amdgcn_mfma_f32_16x16x32_bf16(
              af[m], bf[n], acc[m][n], 0, 0, 0);
    }
  }

  if (g == 3)
    flush_cheap(acc, rs, rowbase + wr * 64, lane);
  else
    flush_full(acc, rs, cs, rowbase + wr * 64, colbase + wc * 64, lane);
}

// ---------------------------------------------------------------------------
// Final scalar reduction.
__global__ __launch_bounds__(1024) void loss_kernel(
    const float* __restrict__ sums, const float* __restrict__ dxyz,
    float* __restrict__ out) {
  const float* rs0 = sums;
  const float* cs0 = sums + 4096;
  const float* rs1 = sums + 2 * 4096;
  const float* cs1 = sums + 3 * 4096;
  const float* rs2 = sums + 4 * 4096;
  const float* cs2 = sums + 5 * 4096;
  const float* rs3 = sums + 6 * 4096;
  int tid = threadIdx.x;
  float acc = 0.0f;
  for (int i = tid; i < BHALF; i += 1024) {
    float dxv = dxyz[i];
    float dyv = dxyz[4096 + i];
    float dzv = dxyz[2 * 4096 + i];
    float lx = logf(rs0[i] + rs1[i]) - TEMP_INV * dxv;
    float ly = logf(cs0[i] + rs2[i]) - TEMP_INV * dyv;
    float lz = logf(cs1[i] + cs2[i]) - TEMP_INV * dzv;
    float lv = logf(rs3[i]) - TEMP_INV * (dxv + dyv + dzv);
    acc += lx + ly + lz + lv;
  }
  __shared__ float red[16];
#pragma unroll
  for (int m = 1; m < 64; m <<= 1) acc += __shfl_xor(acc, m, 64);
  if ((tid & 63) == 0) red[tid >> 6] = acc;
  __syncthreads();
  if (tid == 0) {
    float t = 0.0f;
#pragma unroll
    for (int i = 0; i < 16; ++i) t += red[i];
    out[0] = t * (1.0f / 4096.0f);
  }
}

// ---------------------------------------------------------------------------
extern "C" void kernel_launch(void* const* d_in, const int* in_sizes, int n_in,
                              void* d_out, int out_size, void* d_ws,
                              size_t ws_size, hipStream_t stream) {
  const float* x = (const float*)d_in[0];
  const float* y = (const float*)d_in[1];
  const float* z = (const float*)d_in[2];
  char* ws = (char*)d_ws;
  ushort* nrm1 = (ushort*)ws;                       // 4096*384 bf16
  ushort* nrm2 = nrm1 + (size_t)BHALF * KCAT;       // 4096*384 bf16
  float* sums = (float*)(ws + 2 * (size_t)BHALF * KCAT * sizeof(ushort));
  float* dxyz = sums + 7 * 4096;                    // 3*4096 fp32

  hipMemsetAsync(sums, 0, 7 * 4096 * sizeof(float), stream);
  norm_diag_kernel<<<3 * BHALF / 4, 256, 0, stream>>>(x, y, z, nrm1, nrm2,
                                                      dxyz);
  gram_direct_kernel<<<dim3(32, 32, 4), 256, 0, stream>>>(nrm1, nrm2, sums);
  loss_kernel<<<1, 1024, 0, stream>>>(sums, dxyz, (float*)d_out);
}

// Round 12
// 99.027 us; speedup vs baseline: 1.6043x; 1.6043x over previous
//
#include <hip/hip_runtime.h>
#include <hip/hip_bf16.h>
#include <hip/hip_fp8.h>

// Problem constants
#define BHALF 4096      // B = 8192/2
#define DDIM 128        // feature dim per matrix
#define KCAT 384        // 3*DDIM, packed row width (elements = bytes in fp8)
#define TEMP_INV 10.0f  // 1/TEMP
#define EXP2K 14.426950408889634f  // 10 * log2(e): exp(v*10) = exp2(v*EXP2K)

typedef unsigned char u8;
typedef __attribute__((ext_vector_type(4))) float f32x4;    // 16x16 MFMA acc

// Async global->LDS, 16B per lane. LDS dest is wave-uniform base (HW adds
// lane*16). Global source is per-lane.
__device__ __forceinline__ void gload16(const u8* g, u8* l) {
  __builtin_amdgcn_global_load_lds(
      (const __attribute__((address_space(1))) unsigned int*)g,
      (__attribute__((address_space(3))) unsigned int*)l, 16, 0, 0);
}

// ---------------------------------------------------------------------------
// Fused normalize + diag: one wave per (matrix, row-pair i). Outputs fp8
// e4m3 packed rows nrm1[4096][384], nrm2[4096][384] (bytes) + fp32 diag.
__global__ __launch_bounds__(256) void norm_diag_kernel(
    const float* __restrict__ x, const float* __restrict__ y,
    const float* __restrict__ z, u8* __restrict__ nrm1, u8* __restrict__ nrm2,
    float* __restrict__ dxyz) {
  int wave = threadIdx.x >> 6;
  int lane = threadIdx.x & 63;
  int gi = blockIdx.x * 4 + wave;  // 0 .. 3*4096-1
  int mat = gi >> 12;
  int i = gi & 4095;
  const float* src = (mat == 0 ? x : (mat == 1 ? y : z));
  float2 a = *(const float2*)(src + (size_t)i * DDIM + lane * 2);
  float2 b = *(const float2*)(src + (size_t)(i + BHALF) * DDIM + lane * 2);
  float s1 = a.x * a.x + a.y * a.y;
  float s2 = b.x * b.x + b.y * b.y;
  float d = a.x * b.x + a.y * b.y;
#pragma unroll
  for (int m = 1; m < 64; m <<= 1) {
    s1 += __shfl_xor(s1, m, 64);
    s2 += __shfl_xor(s2, m, 64);
    d += __shfl_xor(d, m, 64);
  }
  float r1 = 1.0f / fmaxf(sqrtf(s1), 1e-12f);
  float r2 = 1.0f / fmaxf(sqrtf(s2), 1e-12f);
  __hip_fp8_e4m3 qa0(a.x * r1), qa1(a.y * r1);
  __hip_fp8_e4m3 qb0(b.x * r2), qb1(b.y * r2);
  ushort pa = (ushort)qa0.__x | ((ushort)qa1.__x << 8);
  ushort pb = (ushort)qb0.__x | ((ushort)qb1.__x << 8);
  *(ushort*)(nrm1 + (size_t)i * KCAT + mat * DDIM + lane * 2) = pa;
  *(ushort*)(nrm2 + (size_t)i * KCAT + mat * DDIM + lane * 2) = pb;
  if (lane == 0) dxyz[mat * BHALF + i] = d * r1 * r2;
}

// ---------------------------------------------------------------------------
// Flush helpers (R1/R2/R10-verified; C/D layout is dtype-independent).
// 16x16 C/D layout: col = lane&15, row = (lane>>4)*4 + r.

__device__ __forceinline__ void flush_cheap(f32x4 (&acc)[4][4],
                                            float* __restrict__ dst, int base,
                                            int lane) {
#pragma unroll
  for (int m = 0; m < 4; ++m) {
    float s = 0.0f;
#pragma unroll
    for (int n = 0; n < 4; ++n)
#pragma unroll
      for (int r = 0; r < 4; ++r) s += exp2f(acc[m][n][r] * EXP2K);
    s += __shfl_xor(s, 16, 64);
    s += __shfl_xor(s, 32, 64);
    if (lane < 16) atomicAdd(&dst[base + m * 16 + lane], s);
  }
}

__device__ __forceinline__ void flush_full(f32x4 (&acc)[4][4],
                                           float* __restrict__ rs,
                                           float* __restrict__ cs, int rbase,
                                           int cbase, int lane) {
#pragma unroll
  for (int m = 0; m < 4; ++m)
#pragma unroll
    for (int n = 0; n < 4; ++n)
#pragma unroll
      for (int r = 0; r < 4; ++r)
        acc[m][n][r] = exp2f(acc[m][n][r] * EXP2K);

#pragma unroll
  for (int m = 0; m < 4; ++m) {
    float rsum[4];
#pragma unroll
    for (int r = 0; r < 4; ++r)
      rsum[r] = acc[m][0][r] + acc[m][1][r] + acc[m][2][r] + acc[m][3][r];
#pragma unroll
    for (int r = 0; r < 4; ++r) {
      rsum[r] += __shfl_xor(rsum[r], 1, 64);
      rsum[r] += __shfl_xor(rsum[r], 2, 64);
      rsum[r] += __shfl_xor(rsum[r], 4, 64);
      rsum[r] += __shfl_xor(rsum[r], 8, 64);
    }
    if ((lane & 15) == 0) {
      int rb = rbase + m * 16 + (lane >> 4) * 4;
#pragma unroll
      for (int r = 0; r < 4; ++r) atomicAdd(&rs[rb + r], rsum[r]);
    }
  }

#pragma unroll
  for (int n = 0; n < 4; ++n) {
    float csum = 0.0f;
#pragma unroll
    for (int m = 0; m < 4; ++m)
#pragma unroll
      for (int r = 0; r < 4; ++r) csum += acc[m][n][r];
    csum += __shfl_xor(csum, 16, 64);
    csum += __shfl_xor(csum, 32, 64);
    if (lane < 16) atomicAdd(&cs[cbase + n * 16 + lane], csum);
  }
}

// ---------------------------------------------------------------------------
// Gram kernel v8 "fp8 slab": R10's verified structure with fp8 e4m3 inputs.
// 128x128 tile, 4 waves (2x2, wave tile 64x64), mfma_f32_16x16x32_fp8_fp8
// (same issue rate as bf16, HALF the staged bytes/lines; both matrices
// total 3.1 MB -> fit every XCD's 4 MiB L2).
// Slab = K=128: A 128x128 B = 16 KB + B 16 KB staged with ONE
// vmcnt(0)+barrier, then 64 MFMAs/wave. g3 (K=384): 3 slabs, operand-
// swapped; g0/g1/g2: 1 slab. 4096 blocks, 32 KB LDS -> 2-3 blocks/CU.
// LDS: [row 128][128 B] with 16B-slot XOR swizzle slot ^= (row&7)
// (involution; applied on global source and fragment read; gload16's
// linear dest untouched). Fragment read = ds_read_b64 (8 fp8 = K-chunk 8
// at k=(lane>>4)*8, row=lane&15 — same lane->element pattern as bf16).
// sums layout (4096 floats each): [rs0, cs0, rs1, cs1, rs2, cs2, rs3]
__global__ __launch_bounds__(256) void gram_slab_kernel(
    const u8* __restrict__ nrm1, const u8* __restrict__ nrm2,
    float* __restrict__ sums) {
  __shared__ u8 As[128][128];  // 16 KB
  __shared__ u8 Bs[128][128];  // 16 KB

  int tid = threadIdx.x;
  int lane = tid & 63;
  int wave = tid >> 6;  // 0..3
  int wr = wave >> 1;   // 0..1: rows wr*64
  int wc = wave & 1;    // 0..1: cols wc*64
  int g = (blockIdx.z == 0) ? 3 : (int)blockIdx.z - 1;  // heavy g3 first
  int rowbase = blockIdx.x * 128;
  int colbase = blockIdx.y * 128;

  const u8* Ab;
  const u8* Bb;
  int nslab;
  float* rs;
  float* cs;
  if (g == 3) {
    Ab = nrm1;       Bb = nrm2;       nslab = 3;
    rs = sums + 6 * 4096; cs = nullptr;
  } else if (g == 0) {
    Ab = nrm1;       Bb = nrm1 + 128; nslab = 1;
    rs = sums;            cs = sums + 4096;
  } else if (g == 1) {
    Ab = nrm1;       Bb = nrm1 + 256; nslab = 1;
    rs = sums + 2 * 4096; cs = sums + 3 * 4096;
  } else {
    Ab = nrm1 + 128; Bb = nrm1 + 256; nslab = 1;
    rs = sums + 4 * 4096; cs = sums + 5 * 4096;
  }

  // Staging: per load, lane l -> row +(l>>3) (8 rows/load), 16B slot (l&7);
  // source slot pre-swizzled by (l>>3)&7 = row&7 (involution with read).
  int srow = lane >> 3;                       // 0..7
  int sslot = ((lane & 7) ^ srow) << 4;       // byte offset in row
  const u8* gA = Ab + (size_t)(rowbase + wave * 32 + srow) * KCAT + sslot;
  const u8* gB = Bb + (size_t)(colbase + wave * 32 + srow) * KCAT + sslot;

  // Fragment reads: row = grp*16 + rsel; logical byte = kk*32 + fc*8
  // (fc = lane>>4); 16B slot (kk*2 + (fc>>1)) XOR'd by row&7; +8 if fc odd.
  int rsel = lane & 15;
  int r7 = rsel & 7;
  int fc = lane >> 4;
  int sub8 = (fc & 1) << 3;
  int s16 = fc >> 1;  // 0..1

  f32x4 acc[4][4] = {};

  for (int slab = 0; slab < nslab; ++slab) {
    if (slab) {
      __builtin_amdgcn_s_barrier();       // prev slab reads done everywhere
      __builtin_amdgcn_sched_barrier(0);  // keep stage below the barrier
    }
    int k0 = slab * 128;
    // 4 A-loads + 4 B-loads per wave: rows [wave*32 + ld*8, +8).
#pragma unroll
    for (int ld = 0; ld < 4; ++ld) {
      gload16(gA + k0 + (size_t)ld * 8 * KCAT, &As[wave * 32 + ld * 8][0]);
      gload16(gB + k0 + (size_t)ld * 8 * KCAT, &Bs[wave * 32 + ld * 8][0]);
    }
    asm volatile("s_waitcnt vmcnt(0)" ::: "memory");
    __builtin_amdgcn_s_barrier();
    __builtin_amdgcn_sched_barrier(0);  // no LDS-read hoisting above barrier

#pragma unroll
    for (int kk = 0; kk < 4; ++kk) {
      long long a8[4], b8[4];
      int off = (((kk * 2 + s16) ^ r7) << 4) + sub8;
#pragma unroll
      for (int m = 0; m < 4; ++m)
        a8[m] = *(const long long*)&As[wr * 64 + m * 16 + rsel][off];
#pragma unroll
      for (int n = 0; n < 4; ++n)
        b8[n] = *(const long long*)&Bs[wc * 64 + n * 16 + rsel][off];
      if (g == 3) {
#pragma unroll
        for (int m = 0; m < 4; ++m)
#pragma unroll
          for (int n = 0; n < 4; ++n)
            acc[m][n] = __builtin_amdgcn_mfma_f32_16x16x32_fp8_fp8(
                b8[n], a8[m], acc[m][n], 0, 0, 0);
      } else {
#pragma unroll
        for (int m = 0; m < 4; ++m)
#pragma unroll
          for (int n = 0; n < 4; ++n)
            acc[m][n] = __builtin_amdgcn_mfma_f32_16x16x32_fp8_fp8(
                a8[m], b8[n], acc[m][n], 0, 0, 0);
      }
    }
  }

  if (g == 3)
    flush_cheap(acc, rs, rowbase + wr * 64, lane);
  else
    flush_full(acc, rs, cs, rowbase + wr * 64, colbase + wc * 64, lane);
}

// ---------------------------------------------------------------------------
// Final scalar reduction.
__global__ __launch_bounds__(1024) void loss_kernel(
    const float* __restrict__ sums, const float* __restrict__ dxyz,
    float* __restrict__ out) {
  const float* rs0 = sums;
  const float* cs0 = sums + 4096;
  const float* rs1 = sums + 2 * 4096;
  const float* cs1 = sums + 3 * 4096;
  const float* rs2 = sums + 4 * 4096;
  const float* cs2 = sums + 5 * 4096;
  const float* rs3 = sums + 6 * 4096;
  int tid = threadIdx.x;
  float acc = 0.0f;
  for (int i = tid; i < BHALF; i += 1024) {
    float dxv = dxyz[i];
    float dyv = dxyz[4096 + i];
    float dzv = dxyz[2 * 4096 + i];
    float lx = logf(rs0[i] + rs1[i]) - TEMP_INV * dxv;
    float ly = logf(cs0[i] + rs2[i]) - TEMP_INV * dyv;
    float lz = logf(cs1[i] + cs2[i]) - TEMP_INV * dzv;
    float lv = logf(rs3[i]) - TEMP_INV * (dxv + dyv + dzv);
    acc += lx + ly + lz + lv;
  }
  __shared__ float red[16];
#pragma unroll
  for (int m = 1; m < 64; m <<= 1) acc += __shfl_xor(acc, m, 64);
  if ((tid & 63) == 0) red[tid >> 6] = acc;
  __syncthreads();
  if (tid == 0) {
    float t = 0.0f;
#pragma unroll
    for (int i = 0; i < 16; ++i) t += red[i];
    out[0] = t * (1.0f / 4096.0f);
  }
}

// ---------------------------------------------------------------------------
extern "C" void kernel_launch(void* const* d_in, const int* in_sizes, int n_in,
                              void* d_out, int out_size, void* d_ws,
                              size_t ws_size, hipStream_t stream) {
  const float* x = (const float*)d_in[0];
  const float* y = (const float*)d_in[1];
  const float* z = (const float*)d_in[2];
  char* ws = (char*)d_ws;
  u8* nrm1 = (u8*)ws;                               // 4096*384 fp8
  u8* nrm2 = nrm1 + (size_t)BHALF * KCAT;           // 4096*384 fp8
  float* sums = (float*)(ws + 2 * (size_t)BHALF * KCAT);
  float* dxyz = sums + 7 * 4096;                    // 3*4096 fp32

  hipMemsetAsync(sums, 0, 7 * 4096 * sizeof(float), stream);
  norm_diag_kernel<<<3 * BHALF / 4, 256, 0, stream>>>(x, y, z, nrm1, nrm2,
                                                      dxyz);
  gram_slab_kernel<<<dim3(32, 32, 4), 256, 0, stream>>>(nrm1, nrm2, sums);
  loss_kernel<<<1, 1024, 0, stream>>>(sums, dxyz, (float*)d_out);
}

// Round 13
// 78.165 us; speedup vs baseline: 2.0325x; 1.2669x over previous
//
#include <hip/hip_runtime.h>
#include <hip/hip_bf16.h>

// Problem constants
#define BHALF 4096      // B = 8192/2
#define DDIM 128        // feature dim per matrix
#define KCAT 384        // 3*DDIM, packed row width
#define TEMP_INV 10.0f  // 1/TEMP
#define EXP2K 14.426950408889634f  // 10 * log2(e): exp(v*10) = exp2(v*EXP2K)
#define PSTRIDE (64 * 4096)  // one partial-sum array: [slot 64][4096]

typedef __attribute__((ext_vector_type(8))) short short8;   // 8 bf16
typedef __attribute__((ext_vector_type(4))) float f32x4;    // 16x16 MFMA acc

// Async global->LDS, 16B per lane. LDS dest is wave-uniform base (HW adds
// lane*16). Global source is per-lane.
__device__ __forceinline__ void gload16(const ushort* g, ushort* l) {
  __builtin_amdgcn_global_load_lds(
      (const __attribute__((address_space(1))) unsigned int*)g,
      (__attribute__((address_space(3))) unsigned int*)l, 16, 0, 0);
}

// ---------------------------------------------------------------------------
// Fused normalize + diag: one wave per (matrix, row-pair i).
__global__ __launch_bounds__(256) void norm_diag_kernel(
    const float* __restrict__ x, const float* __restrict__ y,
    const float* __restrict__ z, ushort* __restrict__ nrm1,
    ushort* __restrict__ nrm2, float* __restrict__ dxyz) {
  int wave = threadIdx.x >> 6;
  int lane = threadIdx.x & 63;
  int gi = blockIdx.x * 4 + wave;  // 0 .. 3*4096-1
  int mat = gi >> 12;
  int i = gi & 4095;
  const float* src = (mat == 0 ? x : (mat == 1 ? y : z));
  float2 a = *(const float2*)(src + (size_t)i * DDIM + lane * 2);
  float2 b = *(const float2*)(src + (size_t)(i + BHALF) * DDIM + lane * 2);
  float s1 = a.x * a.x + a.y * a.y;
  float s2 = b.x * b.x + b.y * b.y;
  float d = a.x * b.x + a.y * b.y;
#pragma unroll
  for (int m = 1; m < 64; m <<= 1) {
    s1 += __shfl_xor(s1, m, 64);
    s2 += __shfl_xor(s2, m, 64);
    d += __shfl_xor(d, m, 64);
  }
  float r1 = 1.0f / fmaxf(sqrtf(s1), 1e-12f);
  float r2 = 1.0f / fmaxf(sqrtf(s2), 1e-12f);
  ushort* d1 = nrm1 + (size_t)i * KCAT + mat * DDIM + lane * 2;
  ushort* d2 = nrm2 + (size_t)i * KCAT + mat * DDIM + lane * 2;
  __hip_bfloat162 o1, o2;
  o1.x = __float2bfloat16(a.x * r1);
  o1.y = __float2bfloat16(a.y * r1);
  o2.x = __float2bfloat16(b.x * r2);
  o2.y = __float2bfloat16(b.y * r2);
  *(__hip_bfloat162*)d1 = o1;
  *(__hip_bfloat162*)d2 = o2;
  if (lane == 0) dxyz[mat * BHALF + i] = d * r1 * r2;
}

// ---------------------------------------------------------------------------
// Flush helpers — plain STORES to per-(block,wave) partial slots (no
// atomics, no contention; each slot written exactly once).
// 16x16 C/D layout (verified R1/R2): col = lane&15, row = (lane>>4)*4 + r.

// g3^T (operand-swapped mfma(b,a)): D[j][i]; reduce over j = regs + xor16 +
// xor32; one value per i (nrm1 row). Slot = bj*2 + wc.
__device__ __forceinline__ void flush_cheap(f32x4 (&acc)[4][4],
                                            float* __restrict__ dst, int base,
                                            int lane) {
#pragma unroll
  for (int m = 0; m < 4; ++m) {
    float s = 0.0f;
#pragma unroll
    for (int n = 0; n < 4; ++n)
#pragma unroll
      for (int r = 0; r < 4; ++r) s += exp2f(acc[m][n][r] * EXP2K);
    s += __shfl_xor(s, 16, 64);
    s += __shfl_xor(s, 32, 64);
    if (lane < 16) dst[base + m * 16 + lane] = s;
  }
}

// Full flush: D[i][j]; rs_slot[i] = sum_j exp (this wave's 64 cols),
// cs_slot[j] = sum_i exp (this wave's 64 rows).
__device__ __forceinline__ void flush_full(f32x4 (&acc)[4][4],
                                           float* __restrict__ rs,
                                           float* __restrict__ cs, int rbase,
                                           int cbase, int lane) {
#pragma unroll
  for (int m = 0; m < 4; ++m)
#pragma unroll
    for (int n = 0; n < 4; ++n)
#pragma unroll
      for (int r = 0; r < 4; ++r)
        acc[m][n][r] = exp2f(acc[m][n][r] * EXP2K);

  // row sums: reduce over cols (n + xor over lane&15)
#pragma unroll
  for (int m = 0; m < 4; ++m) {
    float rsum[4];
#pragma unroll
    for (int r = 0; r < 4; ++r)
      rsum[r] = acc[m][0][r] + acc[m][1][r] + acc[m][2][r] + acc[m][3][r];
#pragma unroll
    for (int r = 0; r < 4; ++r) {
      rsum[r] += __shfl_xor(rsum[r], 1, 64);
      rsum[r] += __shfl_xor(rsum[r], 2, 64);
      rsum[r] += __shfl_xor(rsum[r], 4, 64);
      rsum[r] += __shfl_xor(rsum[r], 8, 64);
    }
    if ((lane & 15) == 0) {
      int rb = rbase + m * 16 + (lane >> 4) * 4;
#pragma unroll
      for (int r = 0; r < 4; ++r) rs[rb + r] = rsum[r];
    }
  }

  // col sums: reduce over rows (m, r, xor16, xor32)
#pragma unroll
  for (int n = 0; n < 4; ++n) {
    float csum = 0.0f;
#pragma unroll
    for (int m = 0; m < 4; ++m)
#pragma unroll
      for (int r = 0; r < 4; ++r) csum += acc[m][n][r];
    csum += __shfl_xor(csum, 16, 64);
    csum += __shfl_xor(csum, 32, 64);
    if (lane < 16) cs[cbase + n * 16 + lane] = csum;
  }
}

// ---------------------------------------------------------------------------
// Gram kernel v9 = R10's 63-us structure + partial-sum stores.
// 128x128 tile, 4 waves (2x2, wave tile 64x64), 16x16x32 bf16 MFMA, BK=128
// slab staged with ONE vmcnt(0)+barrier then 64 MFMAs/wave. g3 (K=384):
// 3 slabs, operand-swapped; g0/g1/g2: 1 slab. 4096 blocks, 64KB LDS.
// parts layout: 7 arrays of [slot 64][4096]:
//   a0 rs0(slot bj*2+wc) a1 cs0(bi*2+wr) a2 rs1 a3 cs1 a4 rs2 a5 cs2 a6 rs3
// sums of exp(G/T): g0 x1.y1^T, g1 x1.z1^T, g2 y1.z1^T, g3 xyz1.xyz2^T.
__global__ __launch_bounds__(256) void gram_slab_kernel(
    const ushort* __restrict__ nrm1, const ushort* __restrict__ nrm2,
    float* __restrict__ parts) {
  __shared__ ushort As[4][128][32];  // 32 KB, kslice-major (64B rows)
  __shared__ ushort Bs[4][128][32];  // 32 KB

  int tid = threadIdx.x;
  int lane = tid & 63;
  int wave = tid >> 6;  // 0..3
  int wr = wave >> 1;   // 0..1: rows wr*64
  int wc = wave & 1;    // 0..1: cols wc*64
  int g = (blockIdx.z == 0) ? 3 : (int)blockIdx.z - 1;  // heavy g3 first
  int bi = blockIdx.x;
  int bj = blockIdx.y;
  int rowbase = bi * 128;
  int colbase = bj * 128;

  const ushort* Ab;
  const ushort* Bb;
  int nslab;
  float* rs;  // row-type slot base (indexed by bj*2+wc)
  float* cs;  // col-type slot base (indexed by bi*2+wr)
  int rslot = (bj * 2 + wc) * 4096;
  int cslot = (bi * 2 + wr) * 4096;
  if (g == 3) {
    Ab = nrm1;       Bb = nrm2;       nslab = 3;
    rs = parts + 6 * PSTRIDE + rslot; cs = nullptr;
  } else if (g == 0) {
    Ab = nrm1;       Bb = nrm1 + 128; nslab = 1;
    rs = parts + 0 * PSTRIDE + rslot; cs = parts + 1 * PSTRIDE + cslot;
  } else if (g == 1) {
    Ab = nrm1;       Bb = nrm1 + 256; nslab = 1;
    rs = parts + 2 * PSTRIDE + rslot; cs = parts + 3 * PSTRIDE + cslot;
  } else {
    Ab = nrm1 + 128; Bb = nrm1 + 256; nslab = 1;
    rs = parts + 4 * PSTRIDE + rslot; cs = parts + 5 * PSTRIDE + cslot;
  }

  // Staging: lane l -> LDS row +(l>>2) (16 rows/load), chunk (l&3); source
  // chunk pre-swizzled by ((l>>3)&3) = ((row mod 16)>>1)&3 (R2-verified).
  int srow = lane >> 2;
  int schunk = ((lane & 3) ^ ((lane >> 3) & 3)) << 3;
  const ushort* gA =
      Ab + (size_t)(rowbase + wave * 32 + srow) * KCAT + schunk;
  const ushort* gB =
      Bb + (size_t)(colbase + wave * 32 + srow) * KCAT + schunk;

  // Fragment reads: row = grp*16 + rsel, logical chunk = lane>>4,
  // physical slot = chunk ^ ((rsel>>1)&3).
  int rsel = lane & 15;
  int slot8 = (((lane >> 4) ^ ((rsel >> 1) & 3)) << 3);

  f32x4 acc[4][4] = {};

  for (int slab = 0; slab < nslab; ++slab) {
    if (slab) {
      __builtin_amdgcn_s_barrier();       // prev slab reads done everywhere
      __builtin_amdgcn_sched_barrier(0);  // keep stage below the barrier
    }
    int k0 = slab * 128;
#pragma unroll
    for (int s = 0; s < 4; ++s) {
#pragma unroll
      for (int rg = 0; rg < 2; ++rg) {
        gload16(gA + k0 + s * 32 + (size_t)rg * 16 * KCAT,
                &As[s][wave * 32 + rg * 16][0]);
        gload16(gB + k0 + s * 32 + (size_t)rg * 16 * KCAT,
                &Bs[s][wave * 32 + rg * 16][0]);
      }
    }
    asm volatile("s_waitcnt vmcnt(0)" ::: "memory");
    __builtin_amdgcn_s_barrier();
    __builtin_amdgcn_sched_barrier(0);  // no LDS-read hoisting above barrier

    if (g == 3) {
#pragma unroll
      for (int kk = 0; kk < 4; ++kk) {
        short8 af[4], bf[4];
#pragma unroll
        for (int m = 0; m < 4; ++m)
          af[m] = *(const short8*)&As[kk][wr * 64 + m * 16 + rsel][slot8];
#pragma unroll
        for (int n = 0; n < 4; ++n)
          bf[n] = *(const short8*)&Bs[kk][wc * 64 + n * 16 + rsel][slot8];
#pragma unroll
        for (int m = 0; m < 4; ++m)
#pragma unroll
          for (int n = 0; n < 4; ++n)
            acc[m][n] = __builtin_amdgcn_mfma_f32_16x16x32_bf16(
                bf[n], af[m], acc[m][n], 0, 0, 0);
      }
    } else {
#pragma unroll
      for (int kk = 0; kk < 4; ++kk) {
        short8 af[4], bf[4];
#pragma unroll
        for (int m = 0; m < 4; ++m)
          af[m] = *(const short8*)&As[kk][wr * 64 + m * 16 + rsel][slot8];
#pragma unroll
        for (int n = 0; n < 4; ++n)
          bf[n] = *(const short8*)&Bs[kk][wc * 64 + n * 16 + rsel][slot8];
#pragma unroll
        for (int m = 0; m < 4; ++m)
#pragma unroll
          for (int n = 0; n < 4; ++n)
            acc[m][n] = __builtin_amdgcn_mfma_f32_16x16x32_bf16(
                af[m], bf[n], acc[m][n], 0, 0, 0);
      }
    }
  }

  if (g == 3)
    flush_cheap(acc, rs, rowbase + wr * 64, lane);
  else
    flush_full(acc, rs, cs, rowbase + wr * 64, colbase + wc * 64, lane);
}

// ---------------------------------------------------------------------------
// Final reduction: combine 64 partial slots per array, compute loss terms,
// atomicAdd scalar. Grid 16 x 256 threads = 4096 threads (one per i).
__global__ __launch_bounds__(256) void loss_kernel(
    const float* __restrict__ parts, const float* __restrict__ dxyz,
    float* __restrict__ out) {
  int i = blockIdx.x * 256 + threadIdx.x;  // 0..4095
  float s[7] = {0, 0, 0, 0, 0, 0, 0};
  for (int p = 0; p < 64; ++p) {
#pragma unroll
    for (int a = 0; a < 7; ++a) s[a] += parts[a * PSTRIDE + p * 4096 + i];
  }
  float dxv = dxyz[i];
  float dyv = dxyz[4096 + i];
  float dzv = dxyz[2 * 4096 + i];
  float lx = logf(s[0] + s[2]) - TEMP_INV * dxv;   // rs0 + rs1
  float ly = logf(s[1] + s[4]) - TEMP_INV * dyv;   // cs0 + rs2
  float lz = logf(s[3] + s[5]) - TEMP_INV * dzv;   // cs1 + cs2
  float lv = logf(s[6]) - TEMP_INV * (dxv + dyv + dzv);  // rs3
  float acc = (lx + ly + lz + lv) * (1.0f / 4096.0f);
#pragma unroll
  for (int m = 1; m < 64; m <<= 1) acc += __shfl_xor(acc, m, 64);
  __shared__ float red[4];
  if ((threadIdx.x & 63) == 0) red[threadIdx.x >> 6] = acc;
  __syncthreads();
  if (threadIdx.x == 0)
    atomicAdd(out, red[0] + red[1] + red[2] + red[3]);
}

// ---------------------------------------------------------------------------
extern "C" void kernel_launch(void* const* d_in, const int* in_sizes, int n_in,
                              void* d_out, int out_size, void* d_ws,
                              size_t ws_size, hipStream_t stream) {
  const float* x = (const float*)d_in[0];
  const float* y = (const float*)d_in[1];
  const float* z = (const float*)d_in[2];
  char* ws = (char*)d_ws;
  ushort* nrm1 = (ushort*)ws;                       // 4096*384 bf16
  ushort* nrm2 = nrm1 + (size_t)BHALF * KCAT;       // 4096*384 bf16
  float* parts = (float*)(ws + 2 * (size_t)BHALF * KCAT * sizeof(ushort));
  float* dxyz = parts + 7 * PSTRIDE;                // 3*4096 fp32

  hipMemsetAsync(d_out, 0, sizeof(float), stream);
  norm_diag_kernel<<<3 * BHALF / 4, 256, 0, stream>>>(x, y, z, nrm1, nrm2,
                                                      dxyz);
  gram_slab_kernel<<<dim3(32, 32, 4), 256, 0, stream>>>(nrm1, nrm2, parts);
  loss_kernel<<<16, 256, 0, stream>>>(parts, dxyz, (float*)d_out);
}

// Round 17
// 73.640 us; speedup vs baseline: 2.1574x; 1.0614x over previous
//
#include <hip/hip_runtime.h>
#include <hip/hip_bf16.h>

// Problem constants
#define BHALF 4096      // B = 8192/2
#define DDIM 128        // feature dim per matrix
#define KCAT 384        // 3*DDIM, packed row width
#define TEMP_INV 10.0f  // 1/TEMP
#define EXP2K 14.426950408889634f  // 10 * log2(e): exp(v*10) = exp2(v*EXP2K)
#define PSTRIDE (64 * 4096)  // one partial-sum array: [slot 64][4096]

typedef __attribute__((ext_vector_type(8))) short short8;   // 8 bf16
typedef __attribute__((ext_vector_type(4))) float f32x4;    // 16x16 MFMA acc

// Async global->LDS, 16B per lane. LDS dest is wave-uniform base (HW adds
// lane*16). Global source is per-lane.
__device__ __forceinline__ void gload16(const ushort* g, ushort* l) {
  __builtin_amdgcn_global_load_lds(
      (const __attribute__((address_space(1))) unsigned int*)g,
      (__attribute__((address_space(3))) unsigned int*)l, 16, 0, 0);
}

// ---------------------------------------------------------------------------
// Fused normalize + diag: one wave per (matrix, row-pair i). [R13 verbatim]
__global__ __launch_bounds__(256) void norm_diag_kernel(
    const float* __restrict__ x, const float* __restrict__ y,
    const float* __restrict__ z, ushort* __restrict__ nrm1,
    ushort* __restrict__ nrm2, float* __restrict__ dxyz) {
  int wave = threadIdx.x >> 6;
  int lane = threadIdx.x & 63;
  int gi = blockIdx.x * 4 + wave;  // 0 .. 3*4096-1
  int mat = gi >> 12;
  int i = gi & 4095;
  const float* src = (mat == 0 ? x : (mat == 1 ? y : z));
  float2 a = *(const float2*)(src + (size_t)i * DDIM + lane * 2);
  float2 b = *(const float2*)(src + (size_t)(i + BHALF) * DDIM + lane * 2);
  float s1 = a.x * a.x + a.y * a.y;
  float s2 = b.x * b.x + b.y * b.y;
  float d = a.x * b.x + a.y * b.y;
#pragma unroll
  for (int m = 1; m < 64; m <<= 1) {
    s1 += __shfl_xor(s1, m, 64);
    s2 += __shfl_xor(s2, m, 64);
    d += __shfl_xor(d, m, 64);
  }
  float r1 = 1.0f / fmaxf(sqrtf(s1), 1e-12f);
  float r2 = 1.0f / fmaxf(sqrtf(s2), 1e-12f);
  ushort* d1 = nrm1 + (size_t)i * KCAT + mat * DDIM + lane * 2;
  ushort* d2 = nrm2 + (size_t)i * KCAT + mat * DDIM + lane * 2;
  __hip_bfloat162 o1, o2;
  o1.x = __float2bfloat16(a.x * r1);
  o1.y = __float2bfloat16(a.y * r1);
  o2.x = __float2bfloat16(b.x * r2);
  o2.y = __float2bfloat16(b.y * r2);
  *(__hip_bfloat162*)d1 = o1;
  *(__hip_bfloat162*)d2 = o2;
  if (lane == 0) dxyz[mat * BHALF + i] = d * r1 * r2;
}

// ---------------------------------------------------------------------------
// Flush helpers — plain STORES to per-(block,wave) partial slots (no
// atomics; each slot written exactly once). [R13 verbatim]
// 16x16 C/D layout (verified R1/R2): col = lane&15, row = (lane>>4)*4 + r.

__device__ __forceinline__ void flush_cheap(f32x4 (&acc)[4][4],
                                            float* __restrict__ dst, int base,
                                            int lane) {
#pragma unroll
  for (int m = 0; m < 4; ++m) {
    float s = 0.0f;
#pragma unroll
    for (int n = 0; n < 4; ++n)
#pragma unroll
      for (int r = 0; r < 4; ++r) s += exp2f(acc[m][n][r] * EXP2K);
    s += __shfl_xor(s, 16, 64);
    s += __shfl_xor(s, 32, 64);
    if (lane < 16) dst[base + m * 16 + lane] = s;
  }
}

__device__ __forceinline__ void flush_full(f32x4 (&acc)[4][4],
                                           float* __restrict__ rs,
                                           float* __restrict__ cs, int rbase,
                                           int cbase, int lane) {
#pragma unroll
  for (int m = 0; m < 4; ++m)
#pragma unroll
    for (int n = 0; n < 4; ++n)
#pragma unroll
      for (int r = 0; r < 4; ++r)
        acc[m][n][r] = exp2f(acc[m][n][r] * EXP2K);

  // row sums: reduce over cols (n + xor over lane&15)
#pragma unroll
  for (int m = 0; m < 4; ++m) {
    float rsum[4];
#pragma unroll
    for (int r = 0; r < 4; ++r)
      rsum[r] = acc[m][0][r] + acc[m][1][r] + acc[m][2][r] + acc[m][3][r];
#pragma unroll
    for (int r = 0; r < 4; ++r) {
      rsum[r] += __shfl_xor(rsum[r], 1, 64);
      rsum[r] += __shfl_xor(rsum[r], 2, 64);
      rsum[r] += __shfl_xor(rsum[r], 4, 64);
      rsum[r] += __shfl_xor(rsum[r], 8, 64);
    }
    if ((lane & 15) == 0) {
      int rb = rbase + m * 16 + (lane >> 4) * 4;
#pragma unroll
      for (int r = 0; r < 4; ++r) rs[rb + r] = rsum[r];
    }
  }

  // col sums: reduce over rows (m, r, xor16, xor32)
#pragma unroll
  for (int n = 0; n < 4; ++n) {
    float csum = 0.0f;
#pragma unroll
    for (int m = 0; m < 4; ++m)
#pragma unroll
      for (int r = 0; r < 4; ++r) csum += acc[m][n][r];
    csum += __shfl_xor(csum, 16, 64);
    csum += __shfl_xor(csum, 32, 64);
    if (lane < 16) cs[cbase + n * 16 + lane] = csum;
  }
}

// ---------------------------------------------------------------------------
// Gram kernel [R13 VERBATIM — passed at gram 58.6 us, 0 conflicts, VGPR 112]:
// 128x128 tile, 4 waves (2x2, wave tile 64x64), 16x16x32 bf16 MFMA, BK=128
// slab staged with ONE vmcnt(0)+barrier then 64 MFMAs/wave. g3 (K=384):
// 3 slabs, operand-swapped; g0/g1/g2: 1 slab. 4096 blocks, 64KB LDS.
// parts layout: 7 arrays of [slot 64][4096]:
//   a0 rs0(slot bj*2+wc) a1 cs0(bi*2+wr) a2 rs1 a3 cs1 a4 rs2 a5 cs2 a6 rs3
__global__ __launch_bounds__(256) void gram_slab_kernel(
    const ushort* __restrict__ nrm1, const ushort* __restrict__ nrm2,
    float* __restrict__ parts) {
  __shared__ ushort As[4][128][32];  // 32 KB, kslice-major (64B rows)
  __shared__ ushort Bs[4][128][32];  // 32 KB

  int tid = threadIdx.x;
  int lane = tid & 63;
  int wave = tid >> 6;  // 0..3
  int wr = wave >> 1;   // 0..1: rows wr*64
  int wc = wave & 1;    // 0..1: cols wc*64
  int g = (blockIdx.z == 0) ? 3 : (int)blockIdx.z - 1;  // heavy g3 first
  int bi = blockIdx.x;
  int bj = blockIdx.y;
  int rowbase = bi * 128;
  int colbase = bj * 128;

  const ushort* Ab;
  const ushort* Bb;
  int nslab;
  float* rs;  // row-type slot base (indexed by bj*2+wc)
  float* cs;  // col-type slot base (indexed by bi*2+wr)
  int rslot = (bj * 2 + wc) * 4096;
  int cslot = (bi * 2 + wr) * 4096;
  if (g == 3) {
    Ab = nrm1;       Bb = nrm2;       nslab = 3;
    rs = parts + 6 * PSTRIDE + rslot; cs = nullptr;
  } else if (g == 0) {
    Ab = nrm1;       Bb = nrm1 + 128; nslab = 1;
    rs = parts + 0 * PSTRIDE + rslot; cs = parts + 1 * PSTRIDE + cslot;
  } else if (g == 1) {
    Ab = nrm1;       Bb = nrm1 + 256; nslab = 1;
    rs = parts + 2 * PSTRIDE + rslot; cs = parts + 3 * PSTRIDE + cslot;
  } else {
    Ab = nrm1 + 128; Bb = nrm1 + 256; nslab = 1;
    rs = parts + 4 * PSTRIDE + rslot; cs = parts + 5 * PSTRIDE + cslot;
  }

  // Staging: lane l -> LDS row +(l>>2) (16 rows/load), chunk (l&3); source
  // chunk pre-swizzled by ((l>>3)&3) = ((row mod 16)>>1)&3 (R2-verified).
  int srow = lane >> 2;
  int schunk = ((lane & 3) ^ ((lane >> 3) & 3)) << 3;
  const ushort* gA =
      Ab + (size_t)(rowbase + wave * 32 + srow) * KCAT + schunk;
  const ushort* gB =
      Bb + (size_t)(colbase + wave * 32 + srow) * KCAT + schunk;

  // Fragment reads: row = grp*16 + rsel, logical chunk = lane>>4,
  // physical slot = chunk ^ ((rsel>>1)&3).
  int rsel = lane & 15;
  int slot8 = (((lane >> 4) ^ ((rsel >> 1) & 3)) << 3);

  f32x4 acc[4][4] = {};

  for (int slab = 0; slab < nslab; ++slab) {
    if (slab) {
      __builtin_amdgcn_s_barrier();       // prev slab reads done everywhere
      __builtin_amdgcn_sched_barrier(0);  // keep stage below the barrier
    }
    int k0 = slab * 128;
#pragma unroll
    for (int s = 0; s < 4; ++s) {
#pragma unroll
      for (int rg = 0; rg < 2; ++rg) {
        gload16(gA + k0 + s * 32 + (size_t)rg * 16 * KCAT,
                &As[s][wave * 32 + rg * 16][0]);
        gload16(gB + k0 + s * 32 + (size_t)rg * 16 * KCAT,
                &Bs[s][wave * 32 + rg * 16][0]);
      }
    }
    asm volatile("s_waitcnt vmcnt(0)" ::: "memory");
    __builtin_amdgcn_s_barrier();
    __builtin_amdgcn_sched_barrier(0);  // no LDS-read hoisting above barrier

    if (g == 3) {
#pragma unroll
      for (int kk = 0; kk < 4; ++kk) {
        short8 af[4], bf[4];
#pragma unroll
        for (int m = 0; m < 4; ++m)
          af[m] = *(const short8*)&As[kk][wr * 64 + m * 16 + rsel][slot8];
#pragma unroll
        for (int n = 0; n < 4; ++n)
          bf[n] = *(const short8*)&Bs[kk][wc * 64 + n * 16 + rsel][slot8];
#pragma unroll
        for (int m = 0; m < 4; ++m)
#pragma unroll
          for (int n = 0; n < 4; ++n)
            acc[m][n] = __builtin_amdgcn_mfma_f32_16x16x32_bf16(
                bf[n], af[m], acc[m][n], 0, 0, 0);
      }
    } else {
#pragma unroll
      for (int kk = 0; kk < 4; ++kk) {
        short8 af[4], bf[4];
#pragma unroll
        for (int m = 0; m < 4; ++m)
          af[m] = *(const short8*)&As[kk][wr * 64 + m * 16 + rsel][slot8];
#pragma unroll
        for (int n = 0; n < 4; ++n)
          bf[n] = *(const short8*)&Bs[kk][wc * 64 + n * 16 + rsel][slot8];
#pragma unroll
        for (int m = 0; m < 4; ++m)
#pragma unroll
          for (int n = 0; n < 4; ++n)
            acc[m][n] = __builtin_amdgcn_mfma_f32_16x16x32_bf16(
                af[m], bf[n], acc[m][n], 0, 0, 0);
      }
    }
  }

  if (g == 3)
    flush_cheap(acc, rs, rowbase + wr * 64, lane);
  else
    flush_full(acc, rs, cs, rowbase + wr * 64, colbase + wc * 64, lane);
}

// ---------------------------------------------------------------------------
// Stage 1: fold the 64 partial slots of each of the 7 arrays.
// Grid 112 x 256 = 28672 threads, one per (array, i). Coalesced: consecutive
// threads -> consecutive i within one array. 7.3 MB read at ~chip BW.
__global__ __launch_bounds__(256) void reduce_parts_kernel(
    const float* __restrict__ parts, float* __restrict__ sums7) {
  int f = blockIdx.x * 256 + threadIdx.x;  // 0 .. 7*4096-1
  int a = f >> 12;
  int i = f & 4095;
  const float* p = parts + (size_t)a * PSTRIDE + i;
  float s = 0.0f;
#pragma unroll 8
  for (int slot = 0; slot < 64; ++slot) s += p[slot * 4096];
  sums7[f] = s;
}

// ---------------------------------------------------------------------------
// Stage 2: final loss from folded sums (163 KB read). Grid 16 x 256.
__global__ __launch_bounds__(256) void loss_kernel(
    const float* __restrict__ s7, const float* __restrict__ dxyz,
    float* __restrict__ out) {
  int i = blockIdx.x * 256 + threadIdx.x;  // 0..4095
  float rs0 = s7[i];
  float cs0 = s7[4096 + i];
  float rs1 = s7[2 * 4096 + i];
  float cs1 = s7[3 * 4096 + i];
  float rs2 = s7[4 * 4096 + i];
  float cs2 = s7[5 * 4096 + i];
  float rs3 = s7[6 * 4096 + i];
  float dxv = dxyz[i];
  float dyv = dxyz[4096 + i];
  float dzv = dxyz[2 * 4096 + i];
  float lx = logf(rs0 + rs1) - TEMP_INV * dxv;
  float ly = logf(cs0 + rs2) - TEMP_INV * dyv;
  float lz = logf(cs1 + cs2) - TEMP_INV * dzv;
  float lv = logf(rs3) - TEMP_INV * (dxv + dyv + dzv);
  float acc = (lx + ly + lz + lv) * (1.0f / 4096.0f);
#pragma unroll
  for (int m = 1; m < 64; m <<= 1) acc += __shfl_xor(acc, m, 64);
  __shared__ float red[4];
  if ((threadIdx.x & 63) == 0) red[threadIdx.x >> 6] = acc;
  __syncthreads();
  if (threadIdx.x == 0)
    atomicAdd(out, red[0] + red[1] + red[2] + red[3]);
}

// ---------------------------------------------------------------------------
extern "C" void kernel_launch(void* const* d_in, const int* in_sizes, int n_in,
                              void* d_out, int out_size, void* d_ws,
                              size_t ws_size, hipStream_t stream) {
  const float* x = (const float*)d_in[0];
  const float* y = (const float*)d_in[1];
  const float* z = (const float*)d_in[2];
  char* ws = (char*)d_ws;
  ushort* nrm1 = (ushort*)ws;                       // 4096*384 bf16
  ushort* nrm2 = nrm1 + (size_t)BHALF * KCAT;       // 4096*384 bf16
  float* parts = (float*)(ws + 2 * (size_t)BHALF * KCAT * sizeof(ushort));
  float* dxyz = parts + 7 * PSTRIDE;                // 3*4096 fp32
  float* sums7 = dxyz + 3 * 4096;                   // 7*4096 fp32

  hipMemsetAsync(d_out, 0, sizeof(float), stream);
  norm_diag_kernel<<<3 * BHALF / 4, 256, 0, stream>>>(x, y, z, nrm1, nrm2,
                                                      dxyz);
  gram_slab_kernel<<<dim3(32, 32, 4), 256, 0, stream>>>(nrm1, nrm2, parts);
  reduce_parts_kernel<<<112, 256, 0, stream>>>(parts, sums7);
  loss_kernel<<<16, 256, 0, stream>>>(sums7, dxyz, (float*)d_out);
}